// Round 3
// baseline (657.482 us; speedup 1.0000x reference)
//
#include <hip/hip_runtime.h>
#include <hip/hip_bf16.h>
#include <stdint.h>

// Problem constants
#define T_TOK 8192
#define DIM 4096
#define ODIM 4096
#define NL 8
#define RANK 16
#define KAUG 4224   // DIM + NL*RANK

// ---------- helpers ----------
__device__ __forceinline__ uint16_t f2b(float x) {
    uint32_t u = __builtin_bit_cast(uint32_t, x);
    u += 0x7fffu + ((u >> 16) & 1u);   // RNE
    return (uint16_t)(u >> 16);
}

typedef __attribute__((ext_vector_type(4))) float floatx4;
typedef __attribute__((ext_vector_type(8))) __bf16 bf16x8;

__device__ __forceinline__ void load_lds16(const uint16_t* g, uint16_t* l) {
    __builtin_amdgcn_global_load_lds(
        (const __attribute__((address_space(1))) uint32_t*)g,
        (__attribute__((address_space(3))) uint32_t*)l, 16, 0, 0);
}
__device__ __forceinline__ void nt_store_u4(uint16_t* p, ushort4 v) {
    __builtin_nontemporal_store(__builtin_bit_cast(unsigned long long, v),
                                (unsigned long long*)p);
}

// ---------- kernel 1: pack W (+lora_b) -> waug ; lora_a -> aall ----------
// blocks [0,4096): W row -> waug base cols + lora_b -> waug aug cols
// blocks [4096,4224): lora_a row -> aall
__global__ __launch_bounds__(256) void pack_w(const float* __restrict__ W,
                                              const float* __restrict__ la,
                                              const float* __restrict__ lb,
                                              uint16_t* __restrict__ waug,
                                              uint16_t* __restrict__ aall) {
    int b = blockIdx.x;
    int tid = threadIdx.x;
    if (b < ODIM) {
        const float4* src = (const float4*)(W + (size_t)b * DIM);
        uint16_t* dst = waug + (size_t)b * KAUG;
#pragma unroll
        for (int k = 0; k < 4; ++k) {
            int i4 = k * 256 + tid;
            float4 v = src[i4];
            ushort4 bv;
            bv.x = f2b(v.x); bv.y = f2b(v.y); bv.z = f2b(v.z); bv.w = f2b(v.w);
            nt_store_u4(dst + (size_t)i4 * 4, bv);
        }
        if (tid < NL * RANK) {
            int l = tid >> 4, r = tid & 15;
            dst[DIM + tid] = f2b(lb[((size_t)l * ODIM + b) * RANK + r]);
        }
    } else {
        int rr = b - ODIM;
        const float4* src = (const float4*)(la + (size_t)rr * DIM);
        uint16_t* dst = aall + (size_t)rr * DIM;
#pragma unroll
        for (int k = 0; k < 4; ++k) {
            int i4 = k * 256 + tid;
            float4 v = src[i4];
            ushort4 bv;
            bv.x = f2b(v.x); bv.y = f2b(v.y); bv.z = f2b(v.z); bv.w = f2b(v.w);
            *(ushort4*)(dst + (size_t)i4 * 4) = bv;
        }
    }
}

// ---------- kernel 2: fused x-pack + MFMA shrink ----------
// 512 blocks x 16 tokens. Reads x fp32, writes bf16 base cols of xaug,
// computes S = x . A_all^T (K=4096, BK=128) via MFMA, writes masked aug cols.
// LDS layout swizzled: slot cc of row r holds global 16B-chunk cc ^ (r&15).
#define SBM 16
__global__ __launch_bounds__(256) void shrink_pack(const float* __restrict__ x,
                                                   const uint16_t* __restrict__ aall,
                                                   const int* __restrict__ idx,
                                                   uint16_t* __restrict__ xaug) {
    __shared__ uint16_t sA[SBM * 128];    // 4 KB
    __shared__ uint16_t sB[128 * 128];    // 32 KB
    int tid = threadIdx.x, lane = tid & 63, wid = tid >> 6;
    int t0 = blockIdx.x * SBM;
    int q = lane >> 4, r16 = lane & 15;

    // B staging (aall): call c stages rows c*16 + (tid>>4), slot tid&15
    int rSB = tid >> 4;                       // 0..15
    int kcB = (tid & 15) ^ (rSB & 15);        // global chunk for this slot
    const uint16_t* gB[8];
    uint16_t* lB[8];
#pragma unroll
    for (int c = 0; c < 8; ++c) {
        gB[c] = aall + (size_t)(c * 16 + rSB) * DIM + kcB * 8;
        lB[c] = sB + c * 2048 + wid * 512;
    }

    floatx4 acc[2];
    acc[0] = (floatx4){0.f, 0.f, 0.f, 0.f};
    acc[1] = (floatx4){0.f, 0.f, 0.f, 0.f};

    for (int k0 = 0; k0 < DIM; k0 += 128) {
        __syncthreads();
#pragma unroll
        for (int c = 0; c < 8; ++c) load_lds16(gB[c] + k0, lB[c]);
        // x: load fp32, convert, write base cols (nt), ds_write swizzled
#pragma unroll
        for (int p = 0; p < 2; ++p) {
            int u = p * 256 + tid;            // 0..511 float4 slots in 16x128 tile
            int row = u >> 5;                 // 0..15
            int c4 = u & 31;                  // float4 col within 128
            float4 v = *(const float4*)(x + (size_t)(t0 + row) * DIM + k0 + c4 * 4);
            ushort4 bv;
            bv.x = f2b(v.x); bv.y = f2b(v.y); bv.z = f2b(v.z); bv.w = f2b(v.w);
            nt_store_u4(xaug + (size_t)(t0 + row) * KAUG + k0 + c4 * 4, bv);
            int chunk = c4 >> 1, half = c4 & 1;
            int slot = chunk ^ (row & 15);
            *(ushort4*)(sA + row * 128 + slot * 8 + half * 4) = bv;
        }
        __syncthreads();
#pragma unroll
        for (int kk = 0; kk < 4; ++kk) {
            int ca = (4 * kk + q) ^ r16;      // swizzled chunk slot
            bf16x8 af = *(const bf16x8*)(sA + r16 * 128 + ca * 8);
#pragma unroll
            for (int j = 0; j < 2; ++j) {
                bf16x8 bv = *(const bf16x8*)(sB + (wid * 32 + j * 16 + r16) * 128 + ca * 8);
                acc[j] = __builtin_amdgcn_mfma_f32_16x16x32_bf16(af, bv, acc[j], 0, 0, 0);
            }
        }
    }
    // epilogue: C/D map col=lane&15 (within 16), row=q*4+e. Mask by adapter id.
    int idxv[4];
#pragma unroll
    for (int e = 0; e < 4; ++e) idxv[e] = idx[t0 + q * 4 + e];
#pragma unroll
    for (int j = 0; j < 2; ++j) {
        int p = wid * 32 + j * 16 + r16;      // 0..127 aug col
        int lp = p >> 4;
#pragma unroll
        for (int e = 0; e < 4; ++e) {
            int t = t0 + q * 4 + e;
            uint16_t v = (idxv[e] == lp) ? f2b(acc[j][e]) : (uint16_t)0;
            xaug[(size_t)t * KAUG + DIM + p] = v;
        }
    }
}

// ---------- kernel 3: bf16 NT GEMM, C[t,o] = sum_k A[t,k]*B[o,k], BK=64 swizzled ----------
#define BM 128
#define BN 128

__global__ __launch_bounds__(256) void gemm_aug(const uint16_t* __restrict__ A,
                                                const uint16_t* __restrict__ B,
                                                float* __restrict__ C) {
    __shared__ uint16_t sA[BM * 64];   // 16 KB
    __shared__ uint16_t sB[BN * 64];   // 16 KB

    int tid = threadIdx.x, lane = tid & 63, wid = tid >> 6;
    // XCD/L2-aware swizzle: same-XCD blocks (lid%8) share one bm panel;
    // 256 concurrent blocks cover 8 bm panels x all 32 bn.
    int lid = blockIdx.x;
    int panel = lid >> 8;                 // 0..7
    int rem = lid & 255;
    int bn = rem >> 3;                    // 0..31
    int bm = (panel << 3) | (rem & 7);    // 0..63
    int wm = (wid & 1) * 64, wn = (wid >> 1) * 64;
    int q = lane >> 4, r16 = lane & 15;

    int rS = tid >> 3;                       // 0..31
    int kcS = (tid & 7) ^ (rS & 7);          // swizzled 16B chunk
    const uint16_t* gA[4];
    const uint16_t* gB[4];
    uint16_t* lA[4];
    uint16_t* lB[4];
#pragma unroll
    for (int c = 0; c < 4; ++c) {
        gA[c] = A + (size_t)(bm * BM + c * 32 + rS) * KAUG + kcS * 8;
        gB[c] = B + (size_t)(bn * BN + c * 32 + rS) * KAUG + kcS * 8;
        lA[c] = sA + c * 2048 + wid * 512;
        lB[c] = sB + c * 2048 + wid * 512;
    }

    int sw0 = (q ^ (r16 & 7)) * 8;
    int sw1 = ((4 + q) ^ (r16 & 7)) * 8;

    floatx4 acc[4][4];
#pragma unroll
    for (int i = 0; i < 4; ++i)
#pragma unroll
        for (int j = 0; j < 4; ++j) acc[i][j] = (floatx4){0.f, 0.f, 0.f, 0.f};

    for (int k0 = 0; k0 < KAUG; k0 += 64) {
        __syncthreads();
#pragma unroll
        for (int c = 0; c < 4; ++c) {
            load_lds16(gA[c] + k0, lA[c]);
            load_lds16(gB[c] + k0, lB[c]);
        }
        __syncthreads();
#pragma unroll
        for (int kk = 0; kk < 2; ++kk) {
            int sw = kk ? sw1 : sw0;
            bf16x8 af[4], bv[4];
#pragma unroll
            for (int i = 0; i < 4; ++i)
                af[i] = *(const bf16x8*)(sA + (wm + i * 16 + r16) * 64 + sw);
#pragma unroll
            for (int j = 0; j < 4; ++j)
                bv[j] = *(const bf16x8*)(sB + (wn + j * 16 + r16) * 64 + sw);
#pragma unroll
            for (int i = 0; i < 4; ++i)
#pragma unroll
                for (int j = 0; j < 4; ++j)
                    acc[i][j] = __builtin_amdgcn_mfma_f32_16x16x32_bf16(af[i], bv[j], acc[i][j], 0, 0, 0);
        }
    }

    // epilogue: C/D mapping col = lane&15, row = (lane>>4)*4 + reg [m89-verified]
    // nontemporal: keep 131 MB of C writes from evicting A/B in L2/L3
#pragma unroll
    for (int i = 0; i < 4; ++i) {
#pragma unroll
        for (int j = 0; j < 4; ++j) {
            int col = bn * BN + wn + j * 16 + r16;
#pragma unroll
            for (int e = 0; e < 4; ++e) {
                int row = bm * BM + wm + i * 16 + q * 4 + e;
                __builtin_nontemporal_store(acc[i][j][e], &C[(size_t)row * ODIM + col]);
            }
        }
    }
}

// ---------- launcher ----------
extern "C" void kernel_launch(void* const* d_in, const int* in_sizes, int n_in,
                              void* d_out, int out_size, void* d_ws, size_t ws_size,
                              hipStream_t stream) {
    const float* x  = (const float*)d_in[0];
    const float* W  = (const float*)d_in[1];
    const float* la = (const float*)d_in[2];
    const float* lb = (const float*)d_in[3];
    const int* idx  = (const int*)d_in[4];
    float* out = (float*)d_out;

    uint16_t* xaug = (uint16_t*)d_ws;                         // [8192][4224] bf16
    uint16_t* waug = xaug + (size_t)T_TOK * KAUG;             // [4096][4224] bf16
    uint16_t* aall = waug + (size_t)ODIM * KAUG;              // [128][4096]  bf16

    hipLaunchKernelGGL(pack_w, dim3(ODIM + NL * RANK), dim3(256), 0, stream,
                       W, la, lb, waug, aall);
    hipLaunchKernelGGL(shrink_pack, dim3(T_TOK / SBM), dim3(256), 0, stream,
                       x, aall, idx, xaug);
    hipLaunchKernelGGL(gemm_aug, dim3((T_TOK / BM) * (ODIM / BN)), dim3(256), 0, stream,
                       xaug, waug, out);
}